// Round 1
// baseline (236.059 us; speedup 1.0000x reference)
//
#include <hip/hip_runtime.h>
#include <hip/hip_bf16.h>

// Problem constants (CeptaBlock): B=4,T=2048,D=2048,P=512,K=16,ALPHA=4,R=32
#define B_ 4
#define T_ 2048
#define D_ 2048
#define P_ 512
#define K_ 16
#define ALPHA_ 4
#define R_ 32
#define NE_ 409        // int(0.8*512) -> excitatory count
#define EPS_ 1e-6f
#define G_ 4           // tokens per block

typedef unsigned short u16;
typedef unsigned int u32;

__device__ __forceinline__ float sigmoidf_(float x) {
  return 1.0f / (1.0f + __expf(-x));
}
__device__ __forceinline__ float bfb2f(u16 u) {
  return __uint_as_float(((u32)u) << 16);
}
__device__ __forceinline__ u16 f2bfb(float f) {
  __hip_bfloat16 h = __float2bfloat16(f);
  return *reinterpret_cast<u16*>(&h);
}
// packed-u32 (2x bf16) helpers: lo16 -> float, hi16 -> float
__device__ __forceinline__ float bflo(u32 u) { return __uint_as_float(u << 16); }
__device__ __forceinline__ float bfhi(u32 u) { return __uint_as_float(u & 0xFFFF0000u); }

// ---------------- K1: rmsnorm1 + gather + perceptron + z/lam, G_ tokens/block ----------------
// Barrier structure: A(h1raw+red) | B(perceptron->tf packed) | C(z/lam) — 3 barriers (was 4).
// inv (rsqrt) is deferred out of h1: h1raw = bf16(x*g1); u = wq*inv*sum(h1raw[idx]*wg).
__global__ __launch_bounds__(256) void k_phase1(
    const float* __restrict__ x, const float* __restrict__ g1,
    const int* __restrict__ idx, const float* __restrict__ wg,
    const float* __restrict__ Wp, const float* __restrict__ U,
    const float* __restrict__ Wgt, const float* __restrict__ bg,
    u16* __restrict__ f_ssm, float* __restrict__ z, float* __restrict__ lam) {
  __shared__ u16 h1[G_][D_];        // 16 KB  bf16(x*g1), inv deferred
  __shared__ u32 tf[G_][P_];        // 8 KB   packed (f<<16)|t  bf16x2
  __shared__ float red[G_][4];
  __shared__ float zp[G_][R_][4];   // 2 KB
  __shared__ float lp[G_][R_][4];   // 2 KB
  // total ~28 KB -> 5-6 blocks/CU (was 36 KB -> 4)

  int tid = threadIdx.x;
  int token0 = blockIdx.x * G_;
  int b = token0 >> 11;
  int t0 = token0 & (T_ - 1);

  // ---- stage A: load x, write h1raw + ss partials ----
  float gv[8];
  {
    const float4* gp = reinterpret_cast<const float4*>(g1 + tid * 8);
    *reinterpret_cast<float4*>(&gv[0]) = gp[0];
    *reinterpret_cast<float4*>(&gv[4]) = gp[1];
  }
#pragma unroll
  for (int tok = 0; tok < G_; tok++) {
    float xv[8];
    const float4* xp = reinterpret_cast<const float4*>(x + (size_t)(token0 + tok) * D_ + tid * 8);
    *reinterpret_cast<float4*>(&xv[0]) = xp[0];
    *reinterpret_cast<float4*>(&xv[4]) = xp[1];
    float ss = 0;
    u16 tmp[8];
#pragma unroll
    for (int i = 0; i < 8; i++) { ss += xv[i] * xv[i]; tmp[i] = f2bfb(xv[i] * gv[i]); }
    *reinterpret_cast<uint4*>(&h1[tok][tid * 8]) = *reinterpret_cast<const uint4*>(tmp);
#pragma unroll
    for (int off = 32; off; off >>= 1) ss += __shfl_down(ss, off);
    if ((tid & 63) == 0) red[tok][tid >> 6] = ss;
  }
  __syncthreads();

  float inv[G_];
#pragma unroll
  for (int tok = 0; tok < G_; tok++)
    inv[tok] = rsqrtf((red[tok][0] + red[tok][1] + red[tok][2] + red[tok][3]) * (1.0f / D_) + EPS_);

  // ---- stage B: perceptron; quant scale computed inline from Wp row ----
#pragma unroll
  for (int j = 0; j < 2; j++) {
    int p = tid + j * 256;
    union { int4 v[4]; int s[16]; } iu;
    const int4* ip = reinterpret_cast<const int4*>(idx + p * K_);
    iu.v[0] = ip[0]; iu.v[1] = ip[1]; iu.v[2] = ip[2]; iu.v[3] = ip[3];
    union { float4 v[4]; float s[16]; } wu;
    const float4* wp = reinterpret_cast<const float4*>(wg + p * K_);
    wu.v[0] = wp[0]; wu.v[1] = wp[1]; wu.v[2] = wp[2]; wu.v[3] = wp[3];
    float aw = 0;
    {
      const float4* qp = reinterpret_cast<const float4*>(Wp + p * K_);
#pragma unroll
      for (int q = 0; q < 4; q++) {
        float4 w = qp[q];
        aw += fabsf(w.x) + fabsf(w.y) + fabsf(w.z) + fabsf(w.w);
      }
    }
    float wqp = ((p < NE_) ? 1.0f : -1.0f) * aw * (1.0f / K_);
#pragma unroll
    for (int tok = 0; tok < G_; tok++) {
      float acc = 0;
#pragma unroll
      for (int k = 0; k < K_; k++) acc += bfb2f(h1[tok][iu.s[k]]) * wu.s[k];
      float u = wqp * inv[tok] * acc;
      float f = sigmoidf_(u);
      tf[tok][p] = ((u32)f2bfb(f) << 16) | (u32)f2bfb(f * u);
      f_ssm[(size_t)(token0 + tok) * P_ + p] = f2bfb(f);
    }
  }
  __syncthreads();

  // ---- stage C: z = t@U, lam = sigmoid(f@Wgt + b); uint4 broadcast reads (8x fewer LDS ops) ----
  int r = tid & 31, g = tid >> 5;  // 32 r x 8 p-groups of 64
  float zs[G_], ls[G_];
#pragma unroll
  for (int tok = 0; tok < G_; tok++) { zs[tok] = 0; ls[tok] = 0; }
  int pb = g * 64;
#pragma unroll 2
  for (int pq = 0; pq < 16; pq++) {
    int p = pb + pq * 4;
    float u0 = U[(p + 0) * R_ + r], u1 = U[(p + 1) * R_ + r];
    float u2 = U[(p + 2) * R_ + r], u3 = U[(p + 3) * R_ + r];
    float w0 = Wgt[(p + 0) * R_ + r], w1 = Wgt[(p + 1) * R_ + r];
    float w2 = Wgt[(p + 2) * R_ + r], w3 = Wgt[(p + 3) * R_ + r];
#pragma unroll
    for (int tok = 0; tok < G_; tok++) {
      uint4 q = *reinterpret_cast<const uint4*>(&tf[tok][p]);
      zs[tok] += bflo(q.x) * u0 + bflo(q.y) * u1 + bflo(q.z) * u2 + bflo(q.w) * u3;
      ls[tok] += bfhi(q.x) * w0 + bfhi(q.y) * w1 + bfhi(q.z) * w2 + bfhi(q.w) * w3;
    }
  }
#pragma unroll
  for (int tok = 0; tok < G_; tok++) {
    zs[tok] += __shfl_down(zs[tok], 32);
    ls[tok] += __shfl_down(ls[tok], 32);
  }
  int wid = tid >> 6;
  if ((tid & 63) < 32) {
#pragma unroll
    for (int tok = 0; tok < G_; tok++) { zp[tok][r][wid] = zs[tok]; lp[tok][r][wid] = ls[tok]; }
  }
  __syncthreads();
  if (tid < R_) {
    float bgr = bg[tid];
    float z4[G_], l4[G_];
#pragma unroll
    for (int tok = 0; tok < G_; tok++) {
      float zz = zp[tok][tid][0] + zp[tok][tid][1] + zp[tok][tid][2] + zp[tok][tid][3];
      float ll = lp[tok][tid][0] + lp[tok][tid][1] + lp[tok][tid][2] + lp[tok][tid][3];
      z4[tok] = zz;
      l4[tok] = sigmoidf_(ll + bgr);
    }
    size_t o = ((size_t)(b * R_ + tid)) * T_ + t0;
    *reinterpret_cast<float4*>(&z[o]) = *reinterpret_cast<const float4*>(z4);
    *reinterpret_cast<float4*>(&lam[o]) = *reinterpret_cast<const float4*>(l4);
  }
}

// ---------------- K2: parallel linear scan over T (one wave per (b,r)) ----------------
__global__ __launch_bounds__(64) void k_scan(
    const float* __restrict__ z, const float* __restrict__ lam,
    const float* __restrict__ state, float* __restrict__ S,
    float* __restrict__ out_state) {
  int br = blockIdx.x;     // b*R + r   (128 total)
  int lane = threadIdx.x;  // 64 lanes, 32 timesteps each
  const float* zr = z + (size_t)br * T_ + lane * 32;
  const float* lr = lam + (size_t)br * T_ + lane * 32;
  float zb[32], lb[32];
#pragma unroll
  for (int i = 0; i < 32; i += 4) {
    *reinterpret_cast<float4*>(&zb[i]) = *reinterpret_cast<const float4*>(&zr[i]);
    *reinterpret_cast<float4*>(&lb[i]) = *reinterpret_cast<const float4*>(&lr[i]);
  }
  float A = 1.0f, Z = 0.0f;
#pragma unroll
  for (int i = 0; i < 32; i++) { Z = lb[i] * Z + zb[i]; A *= lb[i]; }
  for (int off = 1; off < 64; off <<= 1) {
    float Ap = __shfl_up(A, off);
    float Zp = __shfl_up(Z, off);
    if (lane >= off) { Z = A * Zp + Z; A = A * Ap; }
  }
  float s0 = state[br];
  float Ae = __shfl_up(A, 1);
  float Ze = __shfl_up(Z, 1);
  float s = (lane == 0) ? s0 : (Ae * s0 + Ze);
  float sb[32];
#pragma unroll
  for (int i = 0; i < 32; i++) { s = lb[i] * s + zb[i]; sb[i] = s; }
  float* Sr = S + (size_t)br * T_ + lane * 32;
#pragma unroll
  for (int i = 0; i < 32; i += 4)
    *reinterpret_cast<float4*>(&Sr[i]) = *reinterpret_cast<const float4*>(&sb[i]);
  if (lane == 63) out_state[br] = s;  // new_state
}

// ---------------- K3: tilde=S@V, y_ssm, x_after, rmsnorm2, MLP, out ----------------
// 2 barriers (was 3): all HBM/L2 loads issued before a barrier so the barrier's
// vmcnt(0) drain overlaps the latency. inv deferred out of h2 as in phase1.
__global__ __launch_bounds__(256) void k_phase3(
    const float* __restrict__ x, const float* __restrict__ g2,
    const int* __restrict__ idx, const float* __restrict__ wg,
    const float* __restrict__ Wo_s, const float* __restrict__ Wp_m,
    const float* __restrict__ Wo_m, const float* __restrict__ V,
    const float* __restrict__ S, const u16* __restrict__ f_ssm,
    float* __restrict__ out) {
  __shared__ float Sl[G_][R_];
  __shared__ u16 h2[G_][D_];        // 16 KB  bf16(xa*g2), inv deferred
  __shared__ float red[G_][4];

  int tid = threadIdx.x;
  int token0 = blockIdx.x * G_;
  int b = token0 >> 11;
  int t0 = token0 & (T_ - 1);
  int p0 = 2 * tid;

  if (tid < G_ * R_) {
    int tok = tid >> 5, r = tid & 31;
    Sl[tok][r] = S[((size_t)(b * R_ + r)) * T_ + t0 + tok];
  }

  // ---- early global loads: x, g2, f_ssm, quant-scale rows (drained at barrier 1) ----
  float gv[8];
  {
    const float4* gp = reinterpret_cast<const float4*>(g2 + tid * 8);
    *reinterpret_cast<float4*>(&gv[0]) = gp[0];
    *reinterpret_cast<float4*>(&gv[4]) = gp[1];
  }
  float xv[G_][8];
#pragma unroll
  for (int tok = 0; tok < G_; tok++) {
    const float4* xp = reinterpret_cast<const float4*>(x + (size_t)(token0 + tok) * D_ + tid * 8);
    *reinterpret_cast<float4*>(&xv[tok][0]) = xp[0];
    *reinterpret_cast<float4*>(&xv[tok][4]) = xp[1];
  }
  u32 fb[G_];  // packed bf16 f_ssm pair (p0, p0+1)
#pragma unroll
  for (int tok = 0; tok < G_; tok++)
    fb[tok] = *reinterpret_cast<const u32*>(f_ssm + (size_t)(token0 + tok) * P_ + p0);

  float sgn0 = (p0 < NE_) ? 1.0f : -1.0f;
  float sgn1 = (p0 + 1 < NE_) ? 1.0f : -1.0f;
  float fo0, fo1, fom0, fom1, wqm0, wqm1;
  {
    float4 a = *reinterpret_cast<const float4*>(Wo_s + p0 * ALPHA_);
    float4 c = *reinterpret_cast<const float4*>(Wo_s + (p0 + 1) * ALPHA_);
    fo0 = sgn0 * 0.25f * (fabsf(a.x) + fabsf(a.y) + fabsf(a.z) + fabsf(a.w));
    fo1 = sgn1 * 0.25f * (fabsf(c.x) + fabsf(c.y) + fabsf(c.z) + fabsf(c.w));
    float4 e = *reinterpret_cast<const float4*>(Wo_m + p0 * ALPHA_);
    float4 h = *reinterpret_cast<const float4*>(Wo_m + (p0 + 1) * ALPHA_);
    fom0 = sgn0 * 0.25f * (fabsf(e.x) + fabsf(e.y) + fabsf(e.z) + fabsf(e.w));
    fom1 = sgn1 * 0.25f * (fabsf(h.x) + fabsf(h.y) + fabsf(h.z) + fabsf(h.w));
    float aw0 = 0, aw1 = 0;
    const float4* q0 = reinterpret_cast<const float4*>(Wp_m + p0 * K_);
    const float4* q1 = reinterpret_cast<const float4*>(Wp_m + (p0 + 1) * K_);
#pragma unroll
    for (int q = 0; q < 4; q++) {
      float4 wa = q0[q], wb = q1[q];
      aw0 += fabsf(wa.x) + fabsf(wa.y) + fabsf(wa.z) + fabsf(wa.w);
      aw1 += fabsf(wb.x) + fabsf(wb.y) + fabsf(wb.z) + fabsf(wb.w);
    }
    wqm0 = sgn0 * aw0 * (1.0f / K_);
    wqm1 = sgn1 * aw1 * (1.0f / K_);
  }
  __syncthreads();  // barrier 1: Sl ready; all early loads drained

  // ---- tilde = S @ V (Sl via float4 broadcasts; V from L2, coalesced float2) ----
  float til0[G_], til1[G_];
#pragma unroll
  for (int tok = 0; tok < G_; tok++) { til0[tok] = 0; til1[tok] = 0; }
  const float2* V2 = reinterpret_cast<const float2*>(V);
#pragma unroll
  for (int rq = 0; rq < 8; rq++) {
    float4 sq[G_];
#pragma unroll
    for (int tok = 0; tok < G_; tok++)
      sq[tok] = *reinterpret_cast<const float4*>(&Sl[tok][rq * 4]);
#pragma unroll
    for (int i = 0; i < 4; i++) {
      float2 vv = V2[(size_t)(rq * 4 + i) * (P_ / 2) + tid];
#pragma unroll
      for (int tok = 0; tok < G_; tok++) {
        float s = (i == 0) ? sq[tok].x : (i == 1) ? sq[tok].y : (i == 2) ? sq[tok].z : sq[tok].w;
        til0[tok] += s * vv.x;
        til1[tok] += s * vv.y;
      }
    }
  }

  // ---- prefetch MLP gather weights now; barrier 2's vmcnt(0) drain hides the L2 latency ----
  union { int4 v[4]; int s[16]; } iu0, iu1;
  union { float4 v[4]; float s[16]; } wu0, wu1;
  {
    const int4* ip0 = reinterpret_cast<const int4*>(idx + p0 * K_);
    const int4* ip1 = reinterpret_cast<const int4*>(idx + (p0 + 1) * K_);
    const float4* wp0 = reinterpret_cast<const float4*>(wg + p0 * K_);
    const float4* wp1 = reinterpret_cast<const float4*>(wg + (p0 + 1) * K_);
#pragma unroll
    for (int q = 0; q < 4; q++) { iu0.v[q] = ip0[q]; iu1.v[q] = ip1[q]; wu0.v[q] = wp0[q]; wu1.v[q] = wp1[q]; }
  }

  // ---- xa = x + y_ssm (in place in xv); ss partials; h2raw = bf16(xa*g2) ----
#pragma unroll
  for (int tok = 0; tok < G_; tok++) {
    float f0 = bflo(fb[tok]), f1 = bfhi(fb[tok]);
    float val0 = f0 * til0[tok] * fo0;
    float val1 = f1 * til1[tok] * fo1;
    float ss = 0;
#pragma unroll
    for (int a = 0; a < 4; a++) {
      float v0 = xv[tok][a] + val0;
      float v1 = xv[tok][4 + a] + val1;
      xv[tok][a] = v0;
      xv[tok][4 + a] = v1;
      ss += v0 * v0 + v1 * v1;
    }
    u16 tmp[8];
#pragma unroll
    for (int i = 0; i < 8; i++) tmp[i] = f2bfb(xv[tok][i] * gv[i]);
    *reinterpret_cast<uint4*>(&h2[tok][tid * 8]) = *reinterpret_cast<const uint4*>(tmp);
#pragma unroll
    for (int off = 32; off; off >>= 1) ss += __shfl_down(ss, off);
    if ((tid & 63) == 0) red[tok][tid >> 6] = ss;
  }
  __syncthreads();  // barrier 2

  // ---- MLP gather + output (inv applied at accumulate time) ----
#pragma unroll
  for (int tok = 0; tok < G_; tok++) {
    float invt = rsqrtf((red[tok][0] + red[tok][1] + red[tok][2] + red[tok][3]) * (1.0f / D_) + EPS_);
    float acc0 = 0, acc1 = 0;
#pragma unroll
    for (int k = 0; k < K_; k++) {
      acc0 += bfb2f(h2[tok][iu0.s[k]]) * wu0.s[k];
      acc1 += bfb2f(h2[tok][iu1.s[k]]) * wu1.s[k];
    }
    float u0 = wqm0 * invt * acc0, u1 = wqm1 * invt * acc1;
    float f0 = sigmoidf_(u0), f1 = sigmoidf_(u1);
    float val0 = f0 * u0 * fom0, val1 = f1 * u1 * fom1;
    float ov[8];
#pragma unroll
    for (int a = 0; a < 4; a++) {
      ov[a] = xv[tok][a] + val0;
      ov[4 + a] = xv[tok][4 + a] + val1;
    }
    float4* op = reinterpret_cast<float4*>(out + (size_t)(token0 + tok) * D_ + tid * 8);
    op[0] = *reinterpret_cast<const float4*>(&ov[0]);
    op[1] = *reinterpret_cast<const float4*>(&ov[4]);
  }
}

// ---------------- host ----------------
extern "C" void kernel_launch(void* const* d_in, const int* in_sizes, int n_in,
                              void* d_out, int out_size, void* d_ws, size_t ws_size,
                              hipStream_t stream) {
  const float* x     = (const float*)d_in[0];
  const float* state = (const float*)d_in[1];
  const float* g1    = (const float*)d_in[2];
  const float* g2    = (const float*)d_in[3];
  const int*   idx_s = (const int*)d_in[4];
  const float* wg_s  = (const float*)d_in[5];
  const int*   idx_m = (const int*)d_in[6];
  const float* wg_m  = (const float*)d_in[7];
  const float* Wp_s  = (const float*)d_in[8];
  const float* Wo_s  = (const float*)d_in[9];
  const float* Wp_m  = (const float*)d_in[10];
  const float* Wo_m  = (const float*)d_in[11];
  const float* U     = (const float*)d_in[12];
  const float* V     = (const float*)d_in[13];
  const float* Wgt   = (const float*)d_in[14];
  const float* bg    = (const float*)d_in[15];
  float* out = (float*)d_out;

  char* ws = (char*)d_ws;
  u16* f_ssm = (u16*)ws;                                    // B*T*P bf16 = 8 MB
  size_t off = (size_t)B_ * T_ * P_ * 2;
  float* z   = (float*)(ws + off); off += (size_t)B_ * R_ * T_ * 4;  // 1 MB
  float* lam = (float*)(ws + off); off += (size_t)B_ * R_ * T_ * 4;  // 1 MB
  float* S   = (float*)(ws + off);                                   // 1 MB

  hipLaunchKernelGGL(k_phase1, dim3(B_ * T_ / G_), dim3(256), 0, stream,
                     x, g1, idx_s, wg_s, Wp_s, U, Wgt, bg, f_ssm, z, lam);
  hipLaunchKernelGGL(k_scan, dim3(B_ * R_), dim3(64), 0, stream,
                     z, lam, state, S, out + (size_t)B_ * T_ * D_);
  hipLaunchKernelGGL(k_phase3, dim3(B_ * T_ / G_), dim3(256), 0, stream,
                     x, g2, idx_m, wg_m, Wo_s, Wp_m, Wo_m, V, S, f_ssm, out);
}

// Round 2
// 215.218 us; speedup vs baseline: 1.0968x; 1.0968x over previous
//
#include <hip/hip_runtime.h>
#include <hip/hip_bf16.h>

// Problem constants (CeptaBlock): B=4,T=2048,D=2048,P=512,K=16,ALPHA=4,R=32
#define B_ 4
#define T_ 2048
#define D_ 2048
#define P_ 512
#define K_ 16
#define ALPHA_ 4
#define R_ 32
#define NE_ 409        // int(0.8*512) -> excitatory count
#define EPS_ 1e-6f
#define G_ 4           // tokens per block

typedef unsigned short u16;
typedef unsigned int u32;

__device__ __forceinline__ float sigmoidf_(float x) {
  return 1.0f / (1.0f + __expf(-x));
}
__device__ __forceinline__ float bfb2f(u16 u) {
  return __uint_as_float(((u32)u) << 16);
}
__device__ __forceinline__ u16 f2bfb(float f) {
  __hip_bfloat16 h = __float2bfloat16(f);
  return *reinterpret_cast<u16*>(&h);
}
// packed-u32 (2x bf16) helpers
__device__ __forceinline__ float bflo(u32 u) { return __uint_as_float(u << 16); }
__device__ __forceinline__ float bfhi(u32 u) { return __uint_as_float(u & 0xFFFF0000u); }

// ---------------- K0: per-neuron quant-dale scalars ----------------
__global__ void k_scalars(const float* __restrict__ Wp_s, const float* __restrict__ Wo_s,
                          const float* __restrict__ Wp_m, const float* __restrict__ Wo_m,
                          float* __restrict__ wq_s, float* __restrict__ fo_s,
                          float* __restrict__ wq_m, float* __restrict__ fo_m) {
  int p = blockIdx.x * blockDim.x + threadIdx.x;
  if (p >= P_) return;
  float sgn = (p < NE_) ? 1.0f : -1.0f;
  float a = 0, b = 0, c = 0, d = 0;
#pragma unroll
  for (int k = 0; k < K_; k++) {
    a += fabsf(Wp_s[p * K_ + k]);
    c += fabsf(Wp_m[p * K_ + k]);
  }
#pragma unroll
  for (int k = 0; k < ALPHA_; k++) {
    b += fabsf(Wo_s[p * ALPHA_ + k]);
    d += fabsf(Wo_m[p * ALPHA_ + k]);
  }
  wq_s[p] = sgn * a * (1.0f / K_);
  fo_s[p] = sgn * b * (1.0f / ALPHA_);
  wq_m[p] = sgn * c * (1.0f / K_);
  fo_m[p] = sgn * d * (1.0f / ALPHA_);
}

// ---------------- K1: rmsnorm1 + gather + perceptron + z/lam, G_ tokens/block ----------------
// 3 barriers: A(h1raw+red) | B(perceptron->tf packed) | C(z/lam reduce).
// inv deferred out of h1: h1raw = bf16(x*g1); u = wq*inv*sum(h1raw[idx]*wg).
__global__ __launch_bounds__(256) void k_phase1(
    const float* __restrict__ x, const float* __restrict__ g1,
    const int* __restrict__ idx, const float* __restrict__ wg,
    const float* __restrict__ U, const float* __restrict__ Wgt,
    const float* __restrict__ bg, const float* __restrict__ wq,
    u16* __restrict__ f_ssm, float* __restrict__ z, float* __restrict__ lam) {
  __shared__ u16 h1[G_][D_];        // 16 KB  bf16(x*g1), inv deferred
  __shared__ u32 tf[G_][P_];        // 8 KB   packed (f<<16)|t  bf16x2
  __shared__ float red[G_][4];
  __shared__ float zp[G_][R_][4];   // 2 KB
  __shared__ float lp[G_][R_][4];   // 2 KB

  int tid = threadIdx.x;
  int token0 = blockIdx.x * G_;
  int b = token0 >> 11;
  int t0 = token0 & (T_ - 1);

  // ---- stage A: load x, write h1raw + ss partials ----
  float gv[8];
  {
    const float4* gp = reinterpret_cast<const float4*>(g1 + tid * 8);
    *reinterpret_cast<float4*>(&gv[0]) = gp[0];
    *reinterpret_cast<float4*>(&gv[4]) = gp[1];
  }
#pragma unroll
  for (int tok = 0; tok < G_; tok++) {
    float xv[8];
    const float4* xp = reinterpret_cast<const float4*>(x + (size_t)(token0 + tok) * D_ + tid * 8);
    *reinterpret_cast<float4*>(&xv[0]) = xp[0];
    *reinterpret_cast<float4*>(&xv[4]) = xp[1];
    float ss = 0;
    u16 tmp[8];
#pragma unroll
    for (int i = 0; i < 8; i++) { ss += xv[i] * xv[i]; tmp[i] = f2bfb(xv[i] * gv[i]); }
    *reinterpret_cast<uint4*>(&h1[tok][tid * 8]) = *reinterpret_cast<const uint4*>(tmp);
#pragma unroll
    for (int off = 32; off; off >>= 1) ss += __shfl_down(ss, off);
    if ((tid & 63) == 0) red[tok][tid >> 6] = ss;
  }
  __syncthreads();

  float inv[G_];
#pragma unroll
  for (int tok = 0; tok < G_; tok++)
    inv[tok] = rsqrtf((red[tok][0] + red[tok][1] + red[tok][2] + red[tok][3]) * (1.0f / D_) + EPS_);

  // ---- stage B: perceptron; weights in regs, loaded here (short live range) ----
#pragma unroll
  for (int j = 0; j < 2; j++) {
    int p = tid + j * 256;
    union { int4 v[4]; int s[16]; } iu;
    const int4* ip = reinterpret_cast<const int4*>(idx + p * K_);
    iu.v[0] = ip[0]; iu.v[1] = ip[1]; iu.v[2] = ip[2]; iu.v[3] = ip[3];
    union { float4 v[4]; float s[16]; } wu;
    const float4* wp = reinterpret_cast<const float4*>(wg + p * K_);
    wu.v[0] = wp[0]; wu.v[1] = wp[1]; wu.v[2] = wp[2]; wu.v[3] = wp[3];
    float wqp = wq[p];
#pragma unroll
    for (int tok = 0; tok < G_; tok++) {
      float acc = 0;
#pragma unroll
      for (int k = 0; k < K_; k++) acc += bfb2f(h1[tok][iu.s[k]]) * wu.s[k];
      float u = wqp * inv[tok] * acc;
      float f = sigmoidf_(u);
      tf[tok][p] = ((u32)f2bfb(f) << 16) | (u32)f2bfb(f * u);
      f_ssm[(size_t)(token0 + tok) * P_ + p] = f2bfb(f);
    }
  }
  __syncthreads();

  // ---- stage C: z = t@U, lam = sigmoid(f@Wgt + b); uint4 broadcast reads ----
  int r = tid & 31, g = tid >> 5;  // 32 r x 8 p-groups of 64
  float zs[G_], ls[G_];
#pragma unroll
  for (int tok = 0; tok < G_; tok++) { zs[tok] = 0; ls[tok] = 0; }
  int pb = g * 64;
#pragma unroll 2
  for (int pq = 0; pq < 16; pq++) {
    int p = pb + pq * 4;
    float u0 = U[(p + 0) * R_ + r], u1 = U[(p + 1) * R_ + r];
    float u2 = U[(p + 2) * R_ + r], u3 = U[(p + 3) * R_ + r];
    float w0 = Wgt[(p + 0) * R_ + r], w1 = Wgt[(p + 1) * R_ + r];
    float w2 = Wgt[(p + 2) * R_ + r], w3 = Wgt[(p + 3) * R_ + r];
#pragma unroll
    for (int tok = 0; tok < G_; tok++) {
      uint4 q = *reinterpret_cast<const uint4*>(&tf[tok][p]);
      zs[tok] += bflo(q.x) * u0 + bflo(q.y) * u1 + bflo(q.z) * u2 + bflo(q.w) * u3;
      ls[tok] += bfhi(q.x) * w0 + bfhi(q.y) * w1 + bfhi(q.z) * w2 + bfhi(q.w) * w3;
    }
  }
#pragma unroll
  for (int tok = 0; tok < G_; tok++) {
    zs[tok] += __shfl_down(zs[tok], 32);
    ls[tok] += __shfl_down(ls[tok], 32);
  }
  int wid = tid >> 6;
  if ((tid & 63) < 32) {
#pragma unroll
    for (int tok = 0; tok < G_; tok++) { zp[tok][r][wid] = zs[tok]; lp[tok][r][wid] = ls[tok]; }
  }
  __syncthreads();
  if (tid < R_) {
    float bgr = bg[tid];
    float z4[G_], l4[G_];
#pragma unroll
    for (int tok = 0; tok < G_; tok++) {
      float zz = zp[tok][tid][0] + zp[tok][tid][1] + zp[tok][tid][2] + zp[tok][tid][3];
      float ll = lp[tok][tid][0] + lp[tok][tid][1] + lp[tok][tid][2] + lp[tok][tid][3];
      z4[tok] = zz;
      l4[tok] = sigmoidf_(ll + bgr);
    }
    size_t o = ((size_t)(b * R_ + tid)) * T_ + t0;
    *reinterpret_cast<float4*>(&z[o]) = *reinterpret_cast<const float4*>(z4);
    *reinterpret_cast<float4*>(&lam[o]) = *reinterpret_cast<const float4*>(l4);
  }
}

// ---------------- K2: parallel linear scan over T (one wave per (b,r)) ----------------
__global__ __launch_bounds__(64) void k_scan(
    const float* __restrict__ z, const float* __restrict__ lam,
    const float* __restrict__ state, float* __restrict__ S,
    float* __restrict__ out_state) {
  int br = blockIdx.x;     // b*R + r   (128 total)
  int lane = threadIdx.x;  // 64 lanes, 32 timesteps each
  const float* zr = z + (size_t)br * T_ + lane * 32;
  const float* lr = lam + (size_t)br * T_ + lane * 32;
  float zb[32], lb[32];
#pragma unroll
  for (int i = 0; i < 32; i += 4) {
    *reinterpret_cast<float4*>(&zb[i]) = *reinterpret_cast<const float4*>(&zr[i]);
    *reinterpret_cast<float4*>(&lb[i]) = *reinterpret_cast<const float4*>(&lr[i]);
  }
  float A = 1.0f, Z = 0.0f;
#pragma unroll
  for (int i = 0; i < 32; i++) { Z = lb[i] * Z + zb[i]; A *= lb[i]; }
  for (int off = 1; off < 64; off <<= 1) {
    float Ap = __shfl_up(A, off);
    float Zp = __shfl_up(Z, off);
    if (lane >= off) { Z = A * Zp + Z; A = A * Ap; }
  }
  float s0 = state[br];
  float Ae = __shfl_up(A, 1);
  float Ze = __shfl_up(Z, 1);
  float s = (lane == 0) ? s0 : (Ae * s0 + Ze);
  float sb[32];
#pragma unroll
  for (int i = 0; i < 32; i++) { s = lb[i] * s + zb[i]; sb[i] = s; }
  float* Sr = S + (size_t)br * T_ + lane * 32;
#pragma unroll
  for (int i = 0; i < 32; i += 4)
    *reinterpret_cast<float4*>(&Sr[i]) = *reinterpret_cast<const float4*>(&sb[i]);
  if (lane == 63) out_state[br] = s;  // new_state
}

// ---------------- K3: tilde=S@V, y_ssm, x_after, rmsnorm2, MLP, out ----------------
// Round-0 load placement (short live ranges, VGPR~60); 2 barriers via deferred inv.
__global__ __launch_bounds__(256) void k_phase3(
    const float* __restrict__ x, const float* __restrict__ g2,
    const int* __restrict__ idx, const float* __restrict__ wg,
    const float* __restrict__ V, const float* __restrict__ S,
    const u16* __restrict__ f_ssm, const float* __restrict__ fo_s,
    const float* __restrict__ wq_m, const float* __restrict__ fo_m,
    float* __restrict__ out) {
  __shared__ float Sl[G_][R_];
  __shared__ u16 h2[G_][D_];        // 16 KB  bf16(xa*g2), inv deferred
  __shared__ float red[G_][4];

  int tid = threadIdx.x;
  int token0 = blockIdx.x * G_;
  int b = token0 >> 11;
  int t0 = token0 & (T_ - 1);
  int p0 = 2 * tid;

  if (tid < G_ * R_) {
    int tok = tid >> 5, r = tid & 31;
    Sl[tok][r] = S[((size_t)(b * R_ + r)) * T_ + t0 + tok];
  }
  __syncthreads();

  // ---- tilde = S @ V (Sl via float4 broadcasts; V coalesced float2) ----
  float til0[G_], til1[G_];
#pragma unroll
  for (int tok = 0; tok < G_; tok++) { til0[tok] = 0; til1[tok] = 0; }
  const float2* V2 = reinterpret_cast<const float2*>(V);
#pragma unroll
  for (int rq = 0; rq < 8; rq++) {
    float4 sq[G_];
#pragma unroll
    for (int tok = 0; tok < G_; tok++)
      sq[tok] = *reinterpret_cast<const float4*>(&Sl[tok][rq * 4]);
#pragma unroll
    for (int i = 0; i < 4; i++) {
      float2 vv = V2[(size_t)(rq * 4 + i) * (P_ / 2) + tid];
#pragma unroll
      for (int tok = 0; tok < G_; tok++) {
        float s = (i == 0) ? sq[tok].x : (i == 1) ? sq[tok].y : (i == 2) ? sq[tok].z : sq[tok].w;
        til0[tok] += s * vv.x;
        til1[tok] += s * vv.y;
      }
    }
  }

  float2 fo = *reinterpret_cast<const float2*>(fo_s + p0);
  float gv[8];
  {
    const float4* gp = reinterpret_cast<const float4*>(g2 + tid * 8);
    *reinterpret_cast<float4*>(&gv[0]) = gp[0];
    *reinterpret_cast<float4*>(&gv[4]) = gp[1];
  }

  // ---- xa = x + y_ssm; ss partials; h2raw = bf16(xa*g2) ----
  float xa[G_][8];
#pragma unroll
  for (int tok = 0; tok < G_; tok++) {
    u32 ff = *reinterpret_cast<const u32*>(f_ssm + (size_t)(token0 + tok) * P_ + p0);
    float val0 = bflo(ff) * til0[tok] * fo.x;
    float val1 = bfhi(ff) * til1[tok] * fo.y;
    float xv[8];
    const float4* xp = reinterpret_cast<const float4*>(x + (size_t)(token0 + tok) * D_ + tid * 8);
    *reinterpret_cast<float4*>(&xv[0]) = xp[0];
    *reinterpret_cast<float4*>(&xv[4]) = xp[1];
    float ss = 0;
#pragma unroll
    for (int a = 0; a < 4; a++) {
      float v0 = xv[a] + val0;
      float v1 = xv[4 + a] + val1;
      xa[tok][a] = v0;
      xa[tok][4 + a] = v1;
      ss += v0 * v0 + v1 * v1;
    }
    u16 tmp[8];
#pragma unroll
    for (int i = 0; i < 8; i++) tmp[i] = f2bfb(xa[tok][i] * gv[i]);
    *reinterpret_cast<uint4*>(&h2[tok][tid * 8]) = *reinterpret_cast<const uint4*>(tmp);
#pragma unroll
    for (int off = 32; off; off >>= 1) ss += __shfl_down(ss, off);
    if ((tid & 63) == 0) red[tok][tid >> 6] = ss;
  }
  __syncthreads();

  // ---- MLP gather: weights loaded here (round-0 placement, short live range) ----
  union { int4 v[4]; int s[16]; } iu0, iu1;
  union { float4 v[4]; float s[16]; } wu0, wu1;
  {
    const int4* ip0 = reinterpret_cast<const int4*>(idx + p0 * K_);
    const int4* ip1 = reinterpret_cast<const int4*>(idx + (p0 + 1) * K_);
    const float4* wp0 = reinterpret_cast<const float4*>(wg + p0 * K_);
    const float4* wp1 = reinterpret_cast<const float4*>(wg + (p0 + 1) * K_);
#pragma unroll
    for (int q = 0; q < 4; q++) { iu0.v[q] = ip0[q]; iu1.v[q] = ip1[q]; wu0.v[q] = wp0[q]; wu1.v[q] = wp1[q]; }
  }
  float2 wqm = *reinterpret_cast<const float2*>(wq_m + p0);
  float2 fom = *reinterpret_cast<const float2*>(fo_m + p0);

#pragma unroll
  for (int tok = 0; tok < G_; tok++) {
    float invt = rsqrtf((red[tok][0] + red[tok][1] + red[tok][2] + red[tok][3]) * (1.0f / D_) + EPS_);
    float acc0 = 0, acc1 = 0;
#pragma unroll
    for (int k = 0; k < K_; k++) {
      acc0 += bfb2f(h2[tok][iu0.s[k]]) * wu0.s[k];
      acc1 += bfb2f(h2[tok][iu1.s[k]]) * wu1.s[k];
    }
    float u0 = wqm.x * invt * acc0, u1 = wqm.y * invt * acc1;
    float f0 = sigmoidf_(u0), f1 = sigmoidf_(u1);
    float val0 = f0 * u0 * fom.x, val1 = f1 * u1 * fom.y;
    float ov[8];
#pragma unroll
    for (int a = 0; a < 4; a++) {
      ov[a] = xa[tok][a] + val0;
      ov[4 + a] = xa[tok][4 + a] + val1;
    }
    float4* op = reinterpret_cast<float4*>(out + (size_t)(token0 + tok) * D_ + tid * 8);
    op[0] = *reinterpret_cast<const float4*>(&ov[0]);
    op[1] = *reinterpret_cast<const float4*>(&ov[4]);
  }
}

// ---------------- host ----------------
extern "C" void kernel_launch(void* const* d_in, const int* in_sizes, int n_in,
                              void* d_out, int out_size, void* d_ws, size_t ws_size,
                              hipStream_t stream) {
  const float* x     = (const float*)d_in[0];
  const float* state = (const float*)d_in[1];
  const float* g1    = (const float*)d_in[2];
  const float* g2    = (const float*)d_in[3];
  const int*   idx_s = (const int*)d_in[4];
  const float* wg_s  = (const float*)d_in[5];
  const int*   idx_m = (const int*)d_in[6];
  const float* wg_m  = (const float*)d_in[7];
  const float* Wp_s  = (const float*)d_in[8];
  const float* Wo_s  = (const float*)d_in[9];
  const float* Wp_m  = (const float*)d_in[10];
  const float* Wo_m  = (const float*)d_in[11];
  const float* U     = (const float*)d_in[12];
  const float* V     = (const float*)d_in[13];
  const float* Wgt   = (const float*)d_in[14];
  const float* bg    = (const float*)d_in[15];
  float* out = (float*)d_out;

  char* ws = (char*)d_ws;
  float* wq_s = (float*)(ws + 0);
  float* fo_s = (float*)(ws + 2048);
  float* wq_m = (float*)(ws + 4096);
  float* fo_m = (float*)(ws + 6144);
  u16* f_ssm = (u16*)(ws + 8192);                                    // B*T*P bf16 = 8 MB
  size_t off = 8192 + (size_t)B_ * T_ * P_ * 2;
  float* z   = (float*)(ws + off); off += (size_t)B_ * R_ * T_ * 4;  // 1 MB
  float* lam = (float*)(ws + off); off += (size_t)B_ * R_ * T_ * 4;  // 1 MB
  float* S   = (float*)(ws + off);                                   // 1 MB

  hipLaunchKernelGGL(k_scalars, dim3(2), dim3(256), 0, stream,
                     Wp_s, Wo_s, Wp_m, Wo_m, wq_s, fo_s, wq_m, fo_m);
  hipLaunchKernelGGL(k_phase1, dim3(B_ * T_ / G_), dim3(256), 0, stream,
                     x, g1, idx_s, wg_s, U, Wgt, bg, wq_s, f_ssm, z, lam);
  hipLaunchKernelGGL(k_scan, dim3(B_ * R_), dim3(64), 0, stream,
                     z, lam, state, S, out + (size_t)B_ * T_ * D_);
  hipLaunchKernelGGL(k_phase3, dim3(B_ * T_ / G_), dim3(256), 0, stream,
                     x, g2, idx_m, wg_m, V, S, f_ssm, fo_s, wq_m, fo_m, out);
}